// Round 16
// baseline (91.442 us; speedup 1.0000x reference)
//
#include <hip/hip_runtime.h>
#include <hip/hip_bf16.h>

// MultiHeadAttentionLegacy: B=2, S=2048, E=768, H=12, HD=64, G=B*H=24
// Inputs fp32, output fp32; internal bf16 MFMA pipeline.
// Legacy reshape = pure flat re-chunk: [4096][768] buffer == 24 slabs [2048][64].
// Softmax denominator over FULL row; tril mask applied AFTER softmax.
// Q projection pre-scaled by log2(e)/sqrt(64) so attention uses exp2 directly.
//
// R1: pre-convert q/k/v fp32->bf16 (gll staging for both GEMM operands).
// R2 (FAILED): deeper attn LDS pipeline -> worse. Not latency-bound.
// R3 (FAILED): direct per-lane L2 reads -> 2x worse. LDS staging is right.
// R4 (FAILED): fewer rounds via tail-pairing -> slightly worse.
// R5 (WIN): constant-sum bx triplets balance per-CU PV load; XCD-affine GEMM.
// R6 (small WIN): launch_bounds(256,3) + hoisted LDS offsets.
// R7 (small WIN): s_sleep slot stagger 512/1024cy (anti-convoy).
// R8/R9 (FAILED): vt-fused V epilogue had wrong legacy mapping.
// R10 (passed, SLOW): correct vt mapping = stride-12 2B scatter. Fused-vt dead.
// R11 (WIN): separate vtrans + prelude fusion banked. 106.6us.
// R12 (small WIN): counted-vmcnt GEMM loop. 105.4us.
// R13 (WIN): 64x64 GEMM tiles -> 9/CU and 3/CU exact dispatch. 100.1us.
// R14 (WIN): native v_exp_f32 -- OCML expansion was eating the VALU. 91.3us.
// R15 (neutral): attn counted-vmcnt -- drain wasn't exposed. Budget audit:
//   pipe sum ~1.6K cy/round vs 3.07K wall => ~1.5K cy is cross-block
//   serialization residual (per-round serial chain ~650cy x poor overlap).
// R16: full anti-phase stagger. Round ~3K cy; offsets should be thirds
//   (~1000/2000 cy), not R7's 512/1024. s_sleep(16)/s_sleep(32). If neutral,
//   the residual is intra-block chain latency -> declared plateau.

typedef __bf16 bf16;
typedef __attribute__((ext_vector_type(4))) __bf16 bf16x4;
typedef __attribute__((ext_vector_type(8))) __bf16 bf16x8;
typedef __attribute__((ext_vector_type(4))) float f32x4;
typedef __attribute__((ext_vector_type(16))) float f32x16;
typedef __attribute__((ext_vector_type(4))) unsigned int uint4v;

#define MFMA16(a,b,c) __builtin_amdgcn_mfma_f32_16x16x32_bf16((a),(b),(c),0,0,0)
#define MFMA32(a,b,c) __builtin_amdgcn_mfma_f32_32x32x16_bf16((a),(b),(c),0,0,0)

typedef const __attribute__((address_space(1))) unsigned int GU32;
typedef __attribute__((address_space(3))) unsigned int LU32;

__device__ __forceinline__ void gll16(const void* gsrc, void* ldst) {
    __builtin_amdgcn_global_load_lds((GU32*)gsrc, (LU32*)ldst, 16, 0, 0);
}

__device__ __forceinline__ unsigned pk_bf16(float lo, float hi) {
    unsigned r;
    asm("v_cvt_pk_bf16_f32 %0, %1, %2" : "=v"(r) : "v"(lo), "v"(hi));
    return r;
}

// v_permlane32_swap_b32: a.hi32lanes <-> b.lo32lanes
__device__ __forceinline__ void plane32swap(unsigned &a, unsigned &b) {
    asm("v_permlane32_swap_b32 %0, %1" : "+v"(a), "+v"(b));
}

__device__ __forceinline__ bf16x8 frag_words(unsigned w0, unsigned w1, unsigned w2, unsigned w3) {
    union { unsigned u[4]; bf16x8 v; } f;
    f.u[0] = w0; f.u[1] = w1; f.u[2] = w2; f.u[3] = w3;
    return f.v;
}

// ------- fused prelude: cvt (blocks 0..4607) + weight transpose (4608..5183) -------
struct TArg { const float* in; bf16* out; };

__global__ __launch_bounds__(256) void prelude(
    const float* __restrict__ q, const float* __restrict__ k, const float* __restrict__ v,
    bf16* __restrict__ Qb, bf16* __restrict__ Kb, bf16* __restrict__ Vb,
    TArg a0, TArg a1, TArg a2, TArg a3)
{
    __shared__ bf16 tile[64][72];
    const int b = blockIdx.x;
    const int tid = threadIdx.x;
    if (b < 4608) {
        const int m = b / 1536, xx = b % 1536;
        const float* src = m == 0 ? q : m == 1 ? k : v;
        bf16* dst = m == 0 ? Qb : m == 1 ? Kb : Vb;
        const size_t base = (size_t)xx * 2048 + (size_t)tid * 8;
        f32x4 lo = *(const f32x4*)&src[base];
        f32x4 hi = *(const f32x4*)&src[base + 4];
        bf16x8 o;
        for (int j = 0; j < 4; ++j) { o[j] = (bf16)lo[j]; o[4 + j] = (bf16)hi[j]; }
        *(bf16x8*)&dst[base] = o;
    } else {
        const int bb = b - 4608;                // 0..575
        const int wz = bb / 144, bxy = bb % 144;
        TArg ta = wz == 0 ? a0 : wz == 1 ? a1 : wz == 2 ? a2 : a3;
        const int bx = bxy % 12, by = bxy / 12;
        const int k0 = by * 64, n0 = bx * 64;
        for (int qq = 0; qq < 2; ++qq) {
            int idx = qq * 256 + tid;
            int i = idx >> 3, j0 = (idx & 7) * 8;
            const float* src = &ta.in[(size_t)(k0 + i) * 768 + n0 + j0];
            f32x4 lo = *(const f32x4*)&src[0];
            f32x4 hi = *(const f32x4*)&src[4];
            bf16x8 vv;
            for (int j = 0; j < 4; ++j) { vv[j] = (bf16)lo[j]; vv[4 + j] = (bf16)hi[j]; }
            *(bf16x8*)&tile[i][j0] = vv;
        }
        __syncthreads();
        for (int qq = 0; qq < 2; ++qq) {
            int idx = qq * 256 + tid;
            int n = idx >> 3, j0 = (idx & 7) * 8;
            bf16x8 vv;
            for (int jj = 0; jj < 8; ++jj) vv[jj] = tile[j0 + jj][n];
            *(bf16x8*)&ta.out[(size_t)(n0 + n) * 768 + k0 + j0] = vv;
        }
    }
}

// ------- V slab transpose: Vt[g][d][k] = Vp_flat[g*131072 + k*64 + d] -------
__global__ __launch_bounds__(256) void vtrans(const bf16* __restrict__ Vp, bf16* __restrict__ Vt) {
    __shared__ bf16 tile[64][72];
    const int g = blockIdx.y;
    const int k0 = blockIdx.x * 64;
    const bf16* src = Vp + (size_t)g * 131072;
    bf16* dst = Vt + (size_t)g * 131072;
    const int tid = threadIdx.x;
    for (int q = 0; q < 2; ++q) {
        int idx = q * 256 + tid;
        int r = idx >> 3, c = (idx & 7) * 8;
        *(uint4v*)&tile[r][c] = *(const uint4v*)&src[(size_t)(k0 + r) * 64 + c];
    }
    __syncthreads();
    for (int q = 0; q < 2; ++q) {
        int idx = q * 256 + tid;
        int d = idx >> 3, c = (idx & 7) * 8;
        bf16x8 v;
        for (int j = 0; j < 8; ++j) v[j] = tile[c + j][d];
        *(bf16x8*)&dst[(size_t)d * 2048 + k0 + c] = v;
    }
}

// --- GEMM: C[4096x768] = (A @ Bt^T + bias) * scale.  A is bf16 always.
//     MODE 0: C bf16 (proj);  MODE 1: C fp32 (out)
//     R13: 64x64 tiles. MODE0: 2304 blocks = 9/CU exact; MODE1: 768 = 3/CU.
//     XCD-affine: xcd = flat&7 owns 8 row-blocks, cols fastest. R12
//     counted-vmcnt loop (4 gll/wave -> vmcnt(4)). ---
struct GArg { const bf16* A; const bf16* Bt; const float* bias; void* C; float scale; };

template<int MODE>
__global__ __launch_bounds__(256) void gemm_bt_bias(GArg g0, GArg g1, GArg g2) {
    const int flat = blockIdx.x + 12 * blockIdx.y + 768 * blockIdx.z;
    const int xcd = flat & 7;
    const int idx = flat >> 3;          // z=3: 0..287, z=1: 0..95
    const int mat = idx / 96;
    const int rem = idx % 96;
    const int rloc = rem / 12, colb = rem % 12;
    GArg ga = mat == 0 ? g0 : mat == 1 ? g1 : g2;
    const int K = 768, N = 768;
    __shared__ bf16 As[2][64][64];
    __shared__ bf16 Bs[2][64][64];
    const int tid = threadIdx.x;
    const int lane = tid & 63, wave = tid >> 6;
    const int l15 = lane & 15, lg = lane >> 4;
    const int r0 = (xcd * 8 + rloc) * 64, c0 = colb * 64;
    const int wr = (wave >> 1) * 32, wc = (wave & 1) * 32;
    f32x4 acc[2][2] = {};

    const int grow = lane >> 3;                       // 0..7
    const int gcol = 8 * ((lane & 7) ^ (lane >> 3));  // swizzled col

    auto stage = [&](int kt, int buf) {
        const bf16* srcA = &ga.A[(size_t)(r0 + wave * 16 + grow) * K + kt + gcol];
        gll16(srcA, &As[buf][wave * 16][0]);
        gll16(srcA + 8 * K, &As[buf][wave * 16 + 8][0]);
        const bf16* srcB = &ga.Bt[(size_t)(c0 + wave * 16 + grow) * K + kt + gcol];
        gll16(srcB, &Bs[buf][wave * 16][0]);
        gll16(srcB + 8 * K, &Bs[buf][wave * 16 + 8][0]);
    };

    stage(0, 0);                                  // 4 glls in flight

    for (int c = 0; c < 12; ++c) {
        const int buf = c & 1;
        if (c < 11) {
            stage((c + 1) * 64, buf ^ 1);
            asm volatile("s_waitcnt vmcnt(4)" ::: "memory");
        } else {
            asm volatile("s_waitcnt vmcnt(0)" ::: "memory");
        }
        __builtin_amdgcn_s_barrier();             // all waves' stage(c) landed
        __builtin_amdgcn_sched_barrier(0);
        for (int kk = 0; kk < 2; ++kk) {
            bf16x8 af[2], bfr[2];
            for (int i = 0; i < 2; ++i) {
                int row = wr + i * 16 + l15;
                af[i] = *(const bf16x8*)&As[buf][row][(kk * 32 + lg * 8) ^ ((row & 7) * 8)];
            }
            for (int j = 0; j < 2; ++j) {
                int row = wc + j * 16 + l15;
                bfr[j] = *(const bf16x8*)&Bs[buf][row][(kk * 32 + lg * 8) ^ ((row & 7) * 8)];
            }
            __builtin_amdgcn_s_setprio(1);
            for (int i = 0; i < 2; ++i)
                for (int j = 0; j < 2; ++j)
                    acc[i][j] = MFMA16(af[i], bfr[j], acc[i][j]);
            __builtin_amdgcn_s_setprio(0);
        }
        __builtin_amdgcn_sched_barrier(0);
        __builtin_amdgcn_s_barrier();             // all waves done reading buf
    }
    for (int j = 0; j < 2; ++j) {
        int col = c0 + wc + j * 16 + l15;
        float bv = ga.bias[col];
        for (int i = 0; i < 2; ++i) {
            int row = r0 + wr + i * 16 + lg * 4;
            for (int r = 0; r < 4; ++r) {
                float val = (acc[i][j][r] + bv) * ga.scale;
                if constexpr (MODE == 0)
                    ((bf16*)ga.C)[(size_t)(row + r) * N + col] = (bf16)val;
                else
                    ((float*)ga.C)[(size_t)(row + r) * N + col] = val;
            }
        }
    }
}

// ------- attention v16: v15 + full anti-phase stagger (thirds of the round) -------
// Block = 4 waves over 64 q-rows. Wave (wq=w>>1, p=w&1): q rows t0+wq*32..+31,
// k-half p of each 64-chunk. Swapped QK: S-regs q=lane&31, k=(r&3)+8*(r>>2)+4*hi.
// Counted-vmcnt loop (R15); constant-sum bx triplets; XCD-local groups;
// hoisted LDS offsets; s_sleep(16)/s_sleep(32) ~= 1000/2000cy slot offsets.
__global__ __launch_bounds__(256, 3) void attn_kernel(
    const bf16* __restrict__ Qp, const bf16* __restrict__ Kp,
    const bf16* __restrict__ Vtg, bf16* __restrict__ Ob)
{
    const int bid = blockIdx.x;
    const int xcd = bid & 7;
    const int idx = bid >> 3;            // 0..95
    const int t = idx & 31, s = idx >> 5;
    const int bx = (s == 0) ? (31 - t)
                 : (s == 1) ? ((15 - t) & 31)
                 : (((t << 1) & 31) | (t >> 4));
    const int g = xcd * 3 + s;
    const int t0 = bx * 64;
    const int tid = threadIdx.x, lane = tid & 63, w = tid >> 6;
    const int wq = w >> 1, p = w & 1;
    const int l31 = lane & 31, hi = lane >> 5;

    // anti-convoy stagger: thirds of the ~3K cy round period
    if (s == 1) __builtin_amdgcn_s_sleep(16);
    else if (s == 2) __builtin_amdgcn_s_sleep(32);

    __shared__ __align__(16) char smem[32768];
    bf16* KsE = (bf16*)smem;                 // [2][64][64] d-swizzled
    bf16* VsE = (bf16*)(smem + 16384);       // [2][64][64] V^T, k-swizzled

    const bf16* Qg = Qp + (size_t)g * 131072;
    const bf16* Kg = Kp + (size_t)g * 131072;
    const bf16* Vg = Vtg + (size_t)g * 131072;   // [64][2048]
    bf16* Og = Ob + (size_t)g * 131072;

    // Q B-frags in registers: col=q=l31, k-dim d = m*16 + hi*8 + j
    const int qrow = t0 + wq * 32 + l31;
    bf16x8 qB[4];
    for (int m = 0; m < 4; ++m)
        qB[m] = *(const bf16x8*)&Qg[(size_t)qrow * 64 + m * 16 + hi * 8];

    // staging: wave stages 16 rows (2 gll of 8 rows), pre-swizzled source col
    const int srow = w * 16 + (lane >> 3);
    const int scol = 8 * ((lane & 7) ^ (lane >> 3));
    auto stageK = [&](int ch, int b2) {
        const bf16* src = &Kg[(size_t)(ch * 64 + srow) * 64 + scol];
        bf16* dst = KsE + b2 * 4096 + w * 16 * 64;
        gll16(src, dst);
        gll16(src + 8 * 64, dst + 8 * 64);
    };
    auto stageV = [&](int ch, int b2) {
        const bf16* src = &Vg[(size_t)srow * 2048 + ch * 64 + scol];
        bf16* dst = VsE + b2 * 4096 + w * 16 * 64;
        gll16(src, dst);
        gll16(src + 8 * 2048, dst + 8 * 64);
    };

    stageK(0, 0);
    stageV(0, 0);

    f32x16 oacc0 = {}, oacc1 = {};
    float dsum = 0.f;
    const int qmax = t0 + wq * 32 + 31;                 // wave's q range top
    const int qmin = t0 + wq * 32;
    const int kofs = p * 32;                            // wave's k-half offset
    const int swz = (l31 & 7) * 8;

    // hoisted per-lane LDS element offsets (loop-invariant; buffer = +4096)
    int koff[4], voff0[2], voff1[2];
    for (int m = 0; m < 4; ++m)
        koff[m] = (kofs + l31) * 64 + ((m * 16 + hi * 8) ^ swz);
    for (int kt = 0; kt < 2; ++kt) {
        const int col = (kofs + kt * 16 + hi * 8) ^ swz;
        voff0[kt] = l31 * 64 + col;
        voff1[kt] = (32 + l31) * 64 + col;
    }

    for (int c = 0; c < 32; ++c) {
        const int boff = (c & 1) * 4096;
        // stage next chunk FIRST (prev end-barrier guarantees buf^1 is free)
        if (c < 31) {
            stageK(c + 1, (c & 1) ^ 1);
            if (c + 1 <= bx) stageV(c + 1, (c & 1) ^ 1);
        }
        // wait only for chunk c's own loads; chunk c+1's stay in flight.
        if (c == 31)          asm volatile("s_waitcnt vmcnt(0)" ::: "memory");
        else if (c + 1 <= bx) asm volatile("s_waitcnt vmcnt(4)" ::: "memory");
        else                  asm volatile("s_waitcnt vmcnt(2)" ::: "memory");
        __builtin_amdgcn_s_barrier();
        __builtin_amdgcn_sched_barrier(0);

        const int kc = c * 64;
        const bool activ = (kc + kofs <= qmax);         // wave-uniform
        const bool fullc = (kc + kofs + 31 <= qmin);    // wave-uniform

        // ---- QK^T: A = K rows (wave's 32-k half), B = Q regs
        f32x16 s2 = {};
        __builtin_amdgcn_s_setprio(1);
        for (int m = 0; m < 4; ++m) {
            bf16x8 kf = *(const bf16x8*)&KsE[boff + koff[m]];
            s2 = MFMA32(kf, qB[m], s2);
        }
        __builtin_amdgcn_s_setprio(0);

        // ---- native exp2 (Q pre-scaled by log2e/8) + denominator (tree sum)
        float e[16];
        for (int r = 0; r < 16; ++r) e[r] = __builtin_amdgcn_exp2f(s2[r]);
        {
            float p01 = e[0] + e[1],  p23 = e[2] + e[3];
            float p45 = e[4] + e[5],  p67 = e[6] + e[7];
            float p89 = e[8] + e[9],  pab = e[10] + e[11];
            float pcd = e[12] + e[13], pef = e[14] + e[15];
            float q0 = p01 + p23, q1 = p45 + p67, q2 = p89 + pab, q3 = pcd + pef;
            dsum += (q0 + q1) + (q2 + q3);
        }

        if (activ) {
            if (!fullc) {   // diagonal: tril AFTER softmax
                for (int r = 0; r < 16; ++r) {
                    int kg = kc + kofs + (r & 3) + 8 * (r >> 2) + 4 * hi;
                    if (kg > qrow) e[r] = 0.f;
                }
            }
            // ---- pack P to bf16 + permlane32_swap -> 2 PV A-frags, no LDS
            bf16x8 pf[2];
            {
                unsigned a0 = pk_bf16(e[0], e[1]), a1 = pk_bf16(e[2], e[3]);
                unsigned b0 = pk_bf16(e[4], e[5]), b1 = pk_bf16(e[6], e[7]);
                plane32swap(a0, b0); plane32swap(a1, b1);
                pf[0] = frag_words(a0, a1, b0, b1);
                a0 = pk_bf16(e[8], e[9]);   a1 = pk_bf16(e[10], e[11]);
                b0 = pk_bf16(e[12], e[13]); b1 = pk_bf16(e[14], e[15]);
                plane32swap(a0, b0); plane32swap(a1, b1);
                pf[1] = frag_words(a0, a1, b0, b1);
            }
            // ---- PV: A = P frags, B = V^T tile (col d, row k)
            __builtin_amdgcn_s_setprio(1);
            for (int kt = 0; kt < 2; ++kt) {
                bf16x8 v0 = *(const bf16x8*)&VsE[boff + voff0[kt]];
                bf16x8 v1 = *(const bf16x8*)&VsE[boff + voff1[kt]];
                oacc0 = MFMA32(pf[kt], v0, oacc0);
                oacc1 = MFMA32(pf[kt], v1, oacc1);
            }
            __builtin_amdgcn_s_setprio(0);
        }
        __builtin_amdgcn_sched_barrier(0);
        __builtin_amdgcn_s_barrier();   // all waves done reading buf before next stage
    }

    // ---- wave-internal k reduce: lane & lane^32 hold complementary k for q=l31
    dsum += __shfl_xor(dsum, 32);

    // ---- cross-pair reduce via LDS overlay (Ks/Vs regions dead after loop)
    __syncthreads();
    float* Ored = (float*)smem;                 // [pair][q 0-31][d 0-63] = 2 x 8KB
    float* dred = (float*)(smem + 16384);       // [wave][q 0-31] = 512 B
    if (l31 == lane) dred[w * 32 + l31] = dsum; // lanes 0-31 only
    if (p == 1) {
        float* Op = Ored + wq * 2048;
        for (int r = 0; r < 16; ++r) {
            const int qoff = (r & 3) + 8 * (r >> 2) + 4 * hi;
            Op[qoff * 64 + l31]      = oacc0[r];
            Op[qoff * 64 + 32 + l31] = oacc1[r];
        }
    }
    __syncthreads();
    if (p == 0) {
        const float dtot = dsum + dred[(w + 1) * 32 + l31];
        const float rall = 1.0f / dtot;          // valid for q=l31 at every lane
        const float* Op = Ored + wq * 2048;
        for (int r = 0; r < 16; ++r) {
            const int qoff = (r & 3) + 8 * (r >> 2) + 4 * hi;
            const float inv = __shfl(rall, qoff);
            const size_t row = (size_t)(t0 + wq * 32 + qoff) * 64;
            Og[row + l31]      = (bf16)((oacc0[r] + Op[qoff * 64 + l31])      * inv);
            Og[row + 32 + l31] = (bf16)((oacc1[r] + Op[qoff * 64 + 32 + l31]) * inv);
        }
    }
}

// ---------------- host ----------------
extern "C" void kernel_launch(void* const* d_in, const int* in_sizes, int n_in,
                              void* d_out, int out_size, void* d_ws, size_t ws_size,
                              hipStream_t stream) {
    const float* query = (const float*)d_in[0];
    const float* key_  = (const float*)d_in[1];
    const float* value = (const float*)d_in[2];
    const float* Wq = (const float*)d_in[3];
    const float* bq = (const float*)d_in[4];
    const float* Wk = (const float*)d_in[5];
    const float* bk = (const float*)d_in[6];
    const float* Wv = (const float*)d_in[7];
    const float* bv = (const float*)d_in[8];
    const float* Wo = (const float*)d_in[9];
    const float* bo = (const float*)d_in[10];
    float* out = (float*)d_out;

    const size_t MN = (size_t)4096 * 768;
    const size_t WW = (size_t)768 * 768;
    bf16* Qp  = (bf16*)d_ws;
    bf16* Kp  = Qp + MN;
    bf16* Vp  = Kp + MN;     // V projection, standard [4096][768] layout
    bf16* Obf = Vp + MN;
    bf16* Vtg = Obf + MN;    // V^T slabs, written by vtrans
    bf16* WtQ = Vtg + MN;
    bf16* WtK = WtQ + WW;
    bf16* WtV = WtK + WW;
    bf16* WtO = WtV + WW;
    bf16* Vb  = WtO + WW;    // +1 MN slab
    // bf16 activation inputs alias slabs that are dead until after gemm<0>:
    bf16* Qb  = Obf;         // Obf written only by attn (after gemm<0> reads Qb)
    bf16* Kb  = Vtg;         // Vtg written by vtrans (after gemm<0> reads Kb)

    prelude<<<dim3(5184), 256, 0, stream>>>(
        query, key_, value, Qb, Kb, Vb,
        TArg{Wq, WtQ}, TArg{Wk, WtK}, TArg{Wv, WtV}, TArg{Wo, WtO});

    // fold log2(e)/sqrt(HD) into Q so attention uses native exp2
    gemm_bt_bias<0><<<dim3(12, 64, 3), 256, 0, stream>>>(
        GArg{Qb, WtQ, bq, Qp, 0.18033688f},
        GArg{Kb, WtK, bk, Kp, 1.0f},
        GArg{Vb, WtV, bv, Vp, 1.0f});

    vtrans<<<dim3(32, 24), 256, 0, stream>>>(Vp, Vtg);

    attn_kernel<<<dim3(768), 256, 0, stream>>>(Qp, Kp, Vtg, Obf);

    gemm_bt_bias<1><<<dim3(12, 64, 1), 256, 0, stream>>>(
        GArg{Obf, WtO, bo, out, 1.0f},
        GArg{Obf, WtO, bo, out, 1.0f},
        GArg{Obf, WtO, bo, out, 1.0f});
}